// Round 4
// baseline (38.919 us; speedup 1.0000x reference)
//
#include <hip/hip_runtime.h>

// WICC dynamic-connectivity step, fused edge-update + scatter-add.
// B=16, D=1024, E=D*D. All f32.
// Outputs concatenated: phi_out [B*D] then edge_state_next [B*E].
//
// Round 4: R1 structure (block = one (b,dst) row, 1 float4/thread, 65K waves)
// but barrier-free tail: phi_out pre-inited by d2d memcpy, per-wave partial
// sums land via unsafeAtomicAdd. nt hint on the dead es_in stream only.

#define WICC_B 16
#define WICC_D 1024

typedef float vfloat4 __attribute__((ext_vector_type(4)));

__global__ __launch_bounds__(256) void wicc_step_kernel(
    const float* __restrict__ state,     // [B, D]
    const float* __restrict__ J,         // [D, D] (dst, src)
    const float* __restrict__ es_in,     // [B, E]
    float* __restrict__ phi_out,         // [B, D] (pre-initialized to phi)
    float* __restrict__ es_out)          // [B, E]
{
    // Block i -> XCD (i&7) under round-robin dispatch; each XCD owns a
    // contiguous 128-dst slab (512 KB of J) for all batches, batch fastest.
    const int i    = blockIdx.x;          // 0 .. 16383
    const int xcd  = i & 7;
    const int slot = i >> 3;              // 0 .. 2047
    const int b    = slot & 15;           // batch fastest -> J row reused 16x back-to-back
    const int dst  = xcd * 128 + (slot >> 4);

    const int t = threadIdx.x;            // 0..255, each owns 4 src

    const vfloat4* __restrict__ srow = reinterpret_cast<const vfloat4*>(state + (size_t)b * WICC_D);
    const vfloat4* __restrict__ jrow = reinterpret_cast<const vfloat4*>(J + (size_t)dst * WICC_D);
    const size_t ebase4 = ((size_t)b * WICC_D * WICC_D + (size_t)dst * WICC_D) >> 2;

    const vfloat4 s4 = srow[t];
    const vfloat4 j4 = jrow[t];
    const vfloat4 e4 = __builtin_nontemporal_load(reinterpret_cast<const vfloat4*>(es_in) + ebase4 + t);

    const float J_IN = 0.38f, GP = 1e-3f, GM = 1e-3f, BIAS = 2.0f, TH = 0.1675f;

    vfloat4 o4;
    float acc = 0.0f;
    #pragma unroll
    for (int c = 0; c < 4; ++c) {
        const float x  = s4[c] * J_IN;
        const float jj = j4[c];
        const float es = e4[c];
        const float pa = x + jj;
        const float pb = x - jj;
        const float ca = BIAS - es;
        const float cb = BIAS + es;
        const float ra = sqrtf(fmaxf(ca * ca - 1.0f, 0.0f));
        const float rb = sqrtf(fmaxf(cb * cb - 1.0f, 0.0f));
        const float ga = (fabsf(pa) > TH) ? ra : 0.0f;
        const float gb = (fabsf(pb) > TH) ? rb : 0.0f;
        const float esn = es + (GP * (ga - gb) - GM * es);   // DT = 1
        o4[c] = esn;
        acc += esn;
    }

    reinterpret_cast<vfloat4*>(es_out)[ebase4 + t] = o4;

    // Wave-level partial sum; no LDS, no barrier, no store-ack wait.
    #pragma unroll
    for (int off = 32; off > 0; off >>= 1)
        acc += __shfl_down(acc, off, 64);

    if ((t & 63) == 0) {
        const int node = b * WICC_D + dst;
        unsafeAtomicAdd(&phi_out[node], 0.38f * acc);   // J_OUT = 0.38
    }
}

extern "C" void kernel_launch(void* const* d_in, const int* in_sizes, int n_in,
                              void* d_out, int out_size, void* d_ws, size_t ws_size,
                              hipStream_t stream) {
    const float* state = (const float*)d_in[0];   // [B, D]
    const float* phi   = (const float*)d_in[1];   // [B, D]
    const float* J     = (const float*)d_in[2];   // [D, D]
    const float* es    = (const float*)d_in[3];   // [B, E]

    float* phi_out = (float*)d_out;                         // [B*D]
    float* es_out  = (float*)d_out + WICC_B * WICC_D;       // [B*E]

    // phi_out = phi, then atomically accumulate edge contributions onto it.
    hipMemcpyAsync(phi_out, phi, (size_t)WICC_B * WICC_D * sizeof(float),
                   hipMemcpyDeviceToDevice, stream);

    wicc_step_kernel<<<dim3(WICC_B * WICC_D), dim3(256), 0, stream>>>(
        state, J, es, phi_out, es_out);
}

// Round 5
// 30.252 us; speedup vs baseline: 1.2865x; 1.2865x over previous
//
#include <hip/hip_runtime.h>

// WICC dynamic-connectivity step, fused edge-update + scatter-add.
// B=16, D=1024, E=D*D. All f32.
// Outputs concatenated: phi_out [B*D] then edge_state_next [B*E].
//
// Round 5: persistent blocks. 2048 blocks (8/CU, single dispatch cohort),
// each owns one dst row (J row cached in registers) and walks 8 batches.
// Full unroll lets the compiler hoist next-iter loads above this iter's
// barrier (cross-row software pipeline). No nt hints (working set is
// L3-resident across replays). Per-iter LDS slots -> one barrier per row.

#define WICC_B 16
#define WICC_D 1024

typedef float vfloat4 __attribute__((ext_vector_type(4)));

__global__ __launch_bounds__(256) void wicc_step_kernel(
    const float* __restrict__ state,     // [B, D]
    const float* __restrict__ phi,       // [B, D]
    const float* __restrict__ J,         // [D, D] (dst, src)
    const float* __restrict__ es_in,     // [B, E]
    float* __restrict__ phi_out,         // [B, D]
    float* __restrict__ es_out)          // [B, E]
{
    // 2048 blocks. Block j -> XCD (j&7) under round-robin dispatch; each XCD
    // owns a contiguous 128-dst slab (512 KB of J, L2-resident).
    const int j   = blockIdx.x;           // 0..2047
    const int xcd = j & 7;
    const int q   = j >> 3;               // 0..255
    const int h   = q & 1;                // batch half: b in [8h, 8h+8)
    const int dst = xcd * 128 + (q >> 1); // 0..1023

    const int t = threadIdx.x;            // 0..255, each owns 4 src

    // J row for this dst: loaded once, reused for all 8 batches.
    const vfloat4 j4 = reinterpret_cast<const vfloat4*>(J + (size_t)dst * WICC_D)[t];

    const float J_IN = 0.38f, GP = 1e-3f, GM = 1e-3f, BIAS = 2.0f, TH = 0.1675f;

    __shared__ float lds[8][4];

    #pragma unroll
    for (int it = 0; it < 8; ++it) {
        const int b = h * 8 + it;
        const size_t ebase4 = ((size_t)b * WICC_D * WICC_D + (size_t)dst * WICC_D) >> 2;

        const vfloat4 s4 = reinterpret_cast<const vfloat4*>(state + (size_t)b * WICC_D)[t];
        const vfloat4 e4 = reinterpret_cast<const vfloat4*>(es_in)[ebase4 + t];

        vfloat4 o4;
        float acc = 0.0f;
        #pragma unroll
        for (int c = 0; c < 4; ++c) {
            const float x  = s4[c] * J_IN;
            const float jj = j4[c];
            const float es = e4[c];
            const float pa = x + jj;
            const float pb = x - jj;
            const float ca = BIAS - es;
            const float cb = BIAS + es;
            const float ra = sqrtf(fmaxf(ca * ca - 1.0f, 0.0f));
            const float rb = sqrtf(fmaxf(cb * cb - 1.0f, 0.0f));
            const float ga = (fabsf(pa) > TH) ? ra : 0.0f;
            const float gb = (fabsf(pb) > TH) ? rb : 0.0f;
            const float esn = es + (GP * (ga - gb) - GM * es);   // DT = 1
            o4[c] = esn;
            acc += esn;
        }

        reinterpret_cast<vfloat4*>(es_out)[ebase4 + t] = o4;

        // Wave-level partial sums, then one barrier; per-iter LDS slot so the
        // next iteration needs no second barrier (different address).
        #pragma unroll
        for (int off = 32; off > 0; off >>= 1)
            acc += __shfl_down(acc, off, 64);

        if ((t & 63) == 0) lds[it][t >> 6] = acc;
        __syncthreads();
        if (t == 0) {
            const float tot = lds[it][0] + lds[it][1] + lds[it][2] + lds[it][3];
            const int node = b * WICC_D + dst;
            phi_out[node] = phi[node] + 0.38f * tot;   // J_OUT = 0.38
        }
    }
}

extern "C" void kernel_launch(void* const* d_in, const int* in_sizes, int n_in,
                              void* d_out, int out_size, void* d_ws, size_t ws_size,
                              hipStream_t stream) {
    const float* state = (const float*)d_in[0];   // [B, D]
    const float* phi   = (const float*)d_in[1];   // [B, D]
    const float* J     = (const float*)d_in[2];   // [D, D]
    const float* es    = (const float*)d_in[3];   // [B, E]

    float* phi_out = (float*)d_out;                         // [B*D]
    float* es_out  = (float*)d_out + WICC_B * WICC_D;       // [B*E]

    wicc_step_kernel<<<dim3(2048), dim3(256), 0, stream>>>(
        state, phi, J, es, phi_out, es_out);
}

// Round 6
// 28.858 us; speedup vs baseline: 1.3486x; 1.0483x over previous
//
#include <hip/hip_runtime.h>

// WICC dynamic-connectivity step, fused edge-update + scatter-add.
// B=16, D=1024, E=D*D. All f32.
// Outputs concatenated: phi_out [B*D] then edge_state_next [B*E].
//
// Round 6: fully wave-autonomous. One wave = one (b,dst) row: 4 float4/lane,
// in-register shuffle row-sum, lane0 writes phi_out. No LDS, no barrier, no
// atomics, no nt hints (R2's confounder), fire-and-forget stores. Block = 4
// waves on 4 consecutive dst (one contiguous 16KB es chunk). XCD slab remap.

#define WICC_B 16
#define WICC_D 1024

typedef float vfloat4 __attribute__((ext_vector_type(4)));

__global__ __launch_bounds__(256) void wicc_step_kernel(
    const float* __restrict__ state,     // [B, D]
    const float* __restrict__ phi,       // [B, D]
    const float* __restrict__ J,         // [D, D] (dst, src)
    const float* __restrict__ es_in,     // [B, E]
    float* __restrict__ phi_out,         // [B, D]
    float* __restrict__ es_out)          // [B, E]
{
    // 4096 blocks. Block i -> XCD (i&7) (round-robin dispatch). Each XCD owns
    // dst slab [xcd*128, xcd*128+128) for all b: 512 KB of J, L2-resident.
    const int i    = blockIdx.x;          // 0..4095
    const int xcd  = i & 7;
    const int slot = i >> 3;              // 0..511
    const int b    = slot >> 5;           // 0..15 (slowest: es walk contiguous per b)
    const int dgrp = slot & 31;           // 0..31

    const int wave = threadIdx.x >> 6;    // 0..3
    const int lane = threadIdx.x & 63;
    const int dst  = xcd * 128 + dgrp * 4 + wave;   // 4 consecutive rows per block

    const vfloat4* __restrict__ jrow = reinterpret_cast<const vfloat4*>(J + (size_t)dst * WICC_D);
    const vfloat4* __restrict__ srow = reinterpret_cast<const vfloat4*>(state + (size_t)b * WICC_D);
    const size_t ebase4 = ((size_t)b * WICC_D * WICC_D + (size_t)dst * WICC_D) >> 2;
    const vfloat4* __restrict__ erow = reinterpret_cast<const vfloat4*>(es_in) + ebase4;
    vfloat4*       __restrict__ orow = reinterpret_cast<vfloat4*>(es_out) + ebase4;

    // phi for this row: broadcast load, issued early to hide latency.
    const int node = b * WICC_D + dst;
    const float phv = phi[node];

    // Issue the hot es stream first (MLP=4), then J/state (L2/L3 hits).
    vfloat4 e4[4], j4[4], s4[4];
    #pragma unroll
    for (int k = 0; k < 4; ++k) e4[k] = erow[lane + 64 * k];
    #pragma unroll
    for (int k = 0; k < 4; ++k) {
        j4[k] = jrow[lane + 64 * k];
        s4[k] = srow[lane + 64 * k];
    }

    const float J_IN = 0.38f, GP = 1e-3f, GM = 1e-3f, BIAS = 2.0f, TH = 0.1675f;

    float acc = 0.0f;
    #pragma unroll
    for (int k = 0; k < 4; ++k) {
        vfloat4 o4;
        #pragma unroll
        for (int c = 0; c < 4; ++c) {
            const float x  = s4[k][c] * J_IN;
            const float jj = j4[k][c];
            const float es = e4[k][c];
            const float pa = x + jj;
            const float pb = x - jj;
            const float ca = BIAS - es;
            const float cb = BIAS + es;
            const float ra = sqrtf(fmaxf(ca * ca - 1.0f, 0.0f));
            const float rb = sqrtf(fmaxf(cb * cb - 1.0f, 0.0f));
            const float ga = (fabsf(pa) > TH) ? ra : 0.0f;
            const float gb = (fabsf(pb) > TH) ? rb : 0.0f;
            const float esn = es + (GP * (ga - gb) - GM * es);   // DT = 1
            o4[c] = esn;
            acc += esn;
        }
        orow[lane + 64 * k] = o4;   // fire-and-forget
    }

    // In-register wave reduction: no LDS, no barrier.
    #pragma unroll
    for (int off = 32; off > 0; off >>= 1)
        acc += __shfl_down(acc, off, 64);

    if (lane == 0)
        phi_out[node] = phv + 0.38f * acc;   // J_OUT = 0.38
}

extern "C" void kernel_launch(void* const* d_in, const int* in_sizes, int n_in,
                              void* d_out, int out_size, void* d_ws, size_t ws_size,
                              hipStream_t stream) {
    const float* state = (const float*)d_in[0];   // [B, D]
    const float* phi   = (const float*)d_in[1];   // [B, D]
    const float* J     = (const float*)d_in[2];   // [D, D]
    const float* es    = (const float*)d_in[3];   // [B, E]

    float* phi_out = (float*)d_out;                         // [B*D]
    float* es_out  = (float*)d_out + WICC_B * WICC_D;       // [B*E]

    wicc_step_kernel<<<dim3(WICC_D * WICC_B / 4), dim3(256), 0, stream>>>(
        state, phi, J, es, phi_out, es_out);
}

// Round 7
// 25.893 us; speedup vs baseline: 1.5031x; 1.1145x over previous
//
#include <hip/hip_runtime.h>

// WICC dynamic-connectivity step, fused edge-update + scatter-add.
// B=16, D=1024, E=D*D. All f32.
// Outputs concatenated: phi_out [B*D] then edge_state_next [B*E].
//
// Round 7: software-pipelined persistent waves. One wave = one dst x 4
// batches: J row held in registers (reused 4x), es/state for row it+1
// prefetched into ping-pong registers before computing row it (fully
// unrolled -> all static indices). Grid = 1024 blocks = 4/CU single
// cohort, no churn. Raw v_sqrt_f32 via builtin (sqrtf's guarded
// expansion is ~10 insts each, 32/lane). No LDS/barriers/atomics/nt.

#define WICC_B 16
#define WICC_D 1024

typedef float vfloat4 __attribute__((ext_vector_type(4)));

__device__ __forceinline__ float fast_sqrt(float x) {
    return __builtin_amdgcn_sqrtf(x);   // v_sqrt_f32, ~1 ULP
}

__global__ __launch_bounds__(256, 4) void wicc_step_kernel(
    const float* __restrict__ state,     // [B, D]
    const float* __restrict__ phi,       // [B, D]
    const float* __restrict__ J,         // [D, D] (dst, src)
    const float* __restrict__ es_in,     // [B, E]
    float* __restrict__ phi_out,         // [B, D]
    float* __restrict__ es_out)          // [B, E]
{
    // 1024 blocks. Block i -> XCD (i&7) (round-robin dispatch). Each XCD owns
    // dst slab [xcd*128, xcd*128+128): 512 KB of J, L2-resident.
    const int i    = blockIdx.x;          // 0..1023
    const int xcd  = i & 7;
    const int si   = i >> 3;              // 0..127
    const int bgrp = si >> 5;             // 0..3   (batch group: b in [4*bgrp, 4*bgrp+4))
    const int dgrp = si & 31;             // 0..31

    const int wave = threadIdx.x >> 6;    // 0..3
    const int lane = threadIdx.x & 63;
    const int dst  = xcd * 128 + dgrp * 4 + wave;   // 4 consecutive dst per block

    // J row for this dst: registers, reused for all 4 rows.
    const vfloat4* __restrict__ jrow = reinterpret_cast<const vfloat4*>(J + (size_t)dst * WICC_D);
    vfloat4 j4[4];
    #pragma unroll
    for (int k = 0; k < 4; ++k) j4[k] = jrow[lane + 64 * k];

    const float J_IN = 0.38f, GP = 1e-3f, OMG = 1.0f - 1e-3f, BIAS = 2.0f, TH = 0.1675f;

    vfloat4 e[2][4], s[2][4];   // ping-pong prefetch buffers (static-indexed)

    // Prologue: prefetch row it=0.
    {
        const int b0 = bgrp * 4;
        const size_t eb = ((size_t)b0 * WICC_D * WICC_D + (size_t)dst * WICC_D) >> 2;
        const vfloat4* __restrict__ er = reinterpret_cast<const vfloat4*>(es_in) + eb;
        const vfloat4* __restrict__ sr = reinterpret_cast<const vfloat4*>(state + (size_t)b0 * WICC_D);
        #pragma unroll
        for (int k = 0; k < 4; ++k) { e[0][k] = er[lane + 64 * k]; s[0][k] = sr[lane + 64 * k]; }
    }

    #pragma unroll
    for (int it = 0; it < 4; ++it) {
        const int b   = bgrp * 4 + it;
        const int cur = it & 1;
        const int nxt = cur ^ 1;

        // Issue next row's loads BEFORE computing this row (pipeline).
        if (it < 3) {
            const int bn = b + 1;
            const size_t ebn = ((size_t)bn * WICC_D * WICC_D + (size_t)dst * WICC_D) >> 2;
            const vfloat4* __restrict__ ern = reinterpret_cast<const vfloat4*>(es_in) + ebn;
            const vfloat4* __restrict__ srn = reinterpret_cast<const vfloat4*>(state + (size_t)bn * WICC_D);
            #pragma unroll
            for (int k = 0; k < 4; ++k) { e[nxt][k] = ern[lane + 64 * k]; s[nxt][k] = srn[lane + 64 * k]; }
        }

        const int node = b * WICC_D + dst;
        const float phv = phi[node];
        const size_t eb = ((size_t)b * WICC_D * WICC_D + (size_t)dst * WICC_D) >> 2;
        vfloat4* __restrict__ orow = reinterpret_cast<vfloat4*>(es_out) + eb;

        float acc = 0.0f;
        #pragma unroll
        for (int k = 0; k < 4; ++k) {
            vfloat4 o4;
            #pragma unroll
            for (int c = 0; c < 4; ++c) {
                const float x  = s[cur][k][c] * J_IN;
                const float jj = j4[k][c];
                const float es = e[cur][k][c];
                const float pa = x + jj;
                const float pb = x - jj;
                const float ca = BIAS - es;
                const float cb = BIAS + es;
                const float ra = fast_sqrt(fmaxf(ca * ca - 1.0f, 0.0f));
                const float rb = fast_sqrt(fmaxf(cb * cb - 1.0f, 0.0f));
                const float ga = (fabsf(pa) > TH) ? ra : 0.0f;
                const float gb = (fabsf(pb) > TH) ? rb : 0.0f;
                const float esn = fmaf(es, OMG, GP * (ga - gb));   // es*(1-GM) + GP*(ga-gb)
                o4[c] = esn;
                acc += esn;
            }
            orow[lane + 64 * k] = o4;   // fire-and-forget
        }

        // In-register wave reduction: no LDS, no barrier.
        #pragma unroll
        for (int off = 32; off > 0; off >>= 1)
            acc += __shfl_down(acc, off, 64);

        if (lane == 0)
            phi_out[node] = phv + 0.38f * acc;   // J_OUT = 0.38
    }
}

extern "C" void kernel_launch(void* const* d_in, const int* in_sizes, int n_in,
                              void* d_out, int out_size, void* d_ws, size_t ws_size,
                              hipStream_t stream) {
    const float* state = (const float*)d_in[0];   // [B, D]
    const float* phi   = (const float*)d_in[1];   // [B, D]
    const float* J     = (const float*)d_in[2];   // [D, D]
    const float* es    = (const float*)d_in[3];   // [B, E]

    float* phi_out = (float*)d_out;                         // [B*D]
    float* es_out  = (float*)d_out + WICC_B * WICC_D;       // [B*E]

    wicc_step_kernel<<<dim3(1024), dim3(256), 0, stream>>>(
        state, phi, J, es, phi_out, es_out);
}